// Round 11
// baseline (440.835 us; speedup 1.0000x reference)
//
#include <hip/hip_runtime.h>
#include <hip/hip_bf16.h>
#include <stdint.h>

using bf16 = __hip_bfloat16;
typedef __bf16 bf16x8 __attribute__((ext_vector_type(8)));
typedef float f32x4 __attribute__((ext_vector_type(4)));
typedef unsigned short u16x8 __attribute__((ext_vector_type(8)));

#define GLOAD_LDS16(gp, lp)                                                    \
  __builtin_amdgcn_global_load_lds(                                           \
      (const __attribute__((address_space(1))) void*)(gp),                     \
      (__attribute__((address_space(3))) void*)(lp), 16, 0, 0)

#define WAITCNT_VM(N) asm volatile("s_waitcnt vmcnt(" #N ")" ::: "memory")
#define SB0() __builtin_amdgcn_sched_barrier(0)

__device__ inline void store_out(bf16* p, float v)  { *p = __float2bfloat16(v); }
__device__ inline void store_out(float* p, float v) { *p = v; }

// ---------------------------------------------------------------------------
// NT GEMM, 256x128 tile, BK=32. NEW (round 11): B-operand is NOT staged in
// LDS -- each lane loads its B fragments directly global->reg (dbuf, one step
// ahead). B-frag loads are perfectly 64B-line-coalesced: for fixed nf, lanes
// (c16,fr) cover 16 rows x one full 64B line. This halves LDS port traffic
// per block-step (was: write 24KB + read 96KB incl. 2x operand duplication;
// now: A write 16KB + A read 32KB), which round-9/10 modeling identified as
// the binding resource (MFMA 1242 cyc vs LDS ~1900 cyc per dual-step).
// A staged in swizzled LDS ring-3 (48 KB); registers (acc 128 AGPR + ~110
// VGPR = ~238 unified) cap occupancy at 2 blocks/CU -- the measured-best
// point (r9: 2blk=818 TF > r10: 3blk=763 TF).
// 256 thr = 4 waves (2M x 2N), per-wave 128x64 out (8x4 frags 16x16x32).
// C[m][n] = alpha * sum_k A[m][k]*Bt[n][k] (+bias). Col-split epilogue.
// BIAS_AXIS: 0 per-col, 1 per-row. M mult 256, N mult 128, K mult 64 (>=128).
// Chunk order: mt-fastest within XCD chunk (share the B panel -> L2-hot,
// since B is now re-read from cache every step; A is staged once).
//
// LDS: 3 ring slots x 8192 elems (A 256x32). Chunk (16B): row r, col c
// stored at c ^ ((r>>1)&3); read elem(r,c16) = r*32 + ((c16^((r>>1)&3))*8
// [same involution as r9/r10, measured 0 bank conflicts].
//
// Sync per step j: [8 ds_read A(slot j%3); Bload(j+1)->nxt (4 dwordx4);
// stage A(j+2) (4 gload_lds); 32 MFMA(A(j), Bcur)]; vmcnt(4); barrier.
// FIFO at step end: stA(j+1)[4, oldest] B(j+1)[4] stA(j+2)[4] -> vmcnt(4)
// drains stA(j+1)+B(j+1) (B also compiler-guarded). Tails: j=nk-2 vmcnt(0);
// j=nk-1 no wait/barrier. WAR: stage(j+2) targets slot of tile j-1, whose
// reads were consumed by step j-1 MFMAs before its closing barrier.
// ---------------------------------------------------------------------------
template <typename OUT_T, int BIAS_AXIS>
__global__ __launch_bounds__(256, 2) void gemm_bm(
    const bf16* __restrict__ A, const bf16* __restrict__ Bt,
    const float* __restrict__ bias0, const float* __restrict__ bias1,
    OUT_T* __restrict__ out0, OUT_T* __restrict__ out1, int Nsplit,
    int K, int lda, int ldb, int ldc,
    long long sA, long long sB, long long sC, float alpha)
{
    __shared__ __align__(16) bf16 lds[24576];   // 48 KB: 3 x (256x32 A)

    // ---- T1: chunked XCD swizzle, mt-fastest logical order
    const int Mt = gridDim.x, Nt = gridDim.y;
    const int nwg = Mt * Nt * gridDim.z;
    const int hw  = blockIdx.x + Mt * (blockIdx.y + Nt * blockIdx.z);
    const int lg  = (nwg & 7) ? hw : ((hw & 7) * (nwg >> 3) + (hw >> 3));
    const int per = Mt * Nt;
    const int zt  = lg / per;
    const int rem = lg - zt * per;
    const int mt  = rem % Mt;
    const int nt  = rem / Mt;

    A  += (long long)zt * sA;
    Bt += (long long)zt * sB;
    out0 += (long long)zt * sC;
    if (out1) out1 += (long long)zt * sC;

    const int bm = mt * 256;
    const int bn = nt * 128;
    const int t = threadIdx.x, lane = t & 63, w = t >> 6;
    const int wm = w >> 1, wn = w & 1;            // wave grid 2M x 2N
    const int fr = lane & 15, c16 = lane >> 4;

    // ---- A staging: thread t stages chunks {t+256k, k<4}; src col swizzled
    const bf16* gA[4];
    #pragma unroll
    for (int k = 0; k < 4; ++k) {
        const int idx = t + 256 * k, r = idx >> 2, c = idx & 3;
        gA[k] = A + (long long)(bm + r) * lda + ((c ^ ((r >> 1) & 3)) << 3);
    }
    const int dstA = t * 8;    // + k*2048 elems within slot

#define STAGE(JT, SLOTB) do {                                                  \
    GLOAD_LDS16(gA[0] + (JT) * 32, &lds[(SLOTB) + dstA]);                      \
    GLOAD_LDS16(gA[1] + (JT) * 32, &lds[(SLOTB) + dstA + 2048]);               \
    GLOAD_LDS16(gA[2] + (JT) * 32, &lds[(SLOTB) + dstA + 4096]);               \
    GLOAD_LDS16(gA[3] + (JT) * 32, &lds[(SLOTB) + dstA + 6144]);               \
} while (0)

    // ---- B direct-load pointers: lane reads row bn+wn*64+nf*16+fr, k8=c16*8
    const bf16* pBf[4];
    #pragma unroll
    for (int nf = 0; nf < 4; ++nf)
        pBf[nf] = Bt + (long long)(bn + wn * 64 + nf * 16 + fr) * ldb + c16 * 8;

#define BLOAD(JT, DST) do {                                                    \
    _Pragma("unroll") for (int nf = 0; nf < 4; ++nf)                           \
        DST[nf] = *reinterpret_cast<const bf16x8*>(pBf[nf] + (JT) * 32);       \
} while (0)

    // ---- A fragment read offsets (swizzled)
    const int swz8 = (c16 ^ ((fr >> 1) & 3)) << 3;
    const int offA = (wm * 128 + fr) * 32 + swz8;          // + m*512

    const int nk = K >> 5;          // even, >= 4

    f32x4 acc[8][4] = {};
    bf16x8 bU[4], bV[4];

    // prologue: stage A(0); B(0)->bU; stage A(1); drain A(0)+B(0)
    STAGE(0, 0);
    BLOAD(0, bU);
    STAGE(1, 8192);
    WAITCNT_VM(4);
    __builtin_amdgcn_s_barrier();

    // one K-step; BCUR used, BNXT loaded for j+1
#define STEP(J, SLOTB, BCUR, BNXT) do {                                        \
    SB0();                                                                     \
    bf16x8 af[8];                                                              \
    _Pragma("unroll") for (int m = 0; m < 8; ++m)                              \
        af[m] = *reinterpret_cast<const bf16x8*>(&lds[(SLOTB) + offA + m*512]);\
    if ((J) + 1 < nk) BLOAD((J) + 1, BNXT);                                    \
    if ((J) + 2 < nk) {                                                        \
        int s2 = (SLOTB) + 16384; if (s2 >= 24576) s2 -= 24576;                \
        STAGE((J) + 2, s2);                                                    \
    }                                                                          \
    _Pragma("unroll") for (int m = 0; m < 8; ++m)                              \
        _Pragma("unroll") for (int n = 0; n < 4; ++n)                          \
            acc[m][n] = __builtin_amdgcn_mfma_f32_16x16x32_bf16(               \
                af[m], BCUR[n], acc[m][n], 0, 0, 0);                           \
    SB0();                                                                     \
    if ((J) + 2 < nk)      { WAITCNT_VM(4); __builtin_amdgcn_s_barrier(); }    \
    else if ((J) + 1 < nk) { WAITCNT_VM(0); __builtin_amdgcn_s_barrier(); }    \
} while (0)

    int slotb = 0;
    for (int j = 0; j < nk; j += 2) {
        STEP(j, slotb, bU, bV);
        slotb += 8192; if (slotb == 24576) slotb = 0;
        STEP(j + 1, slotb, bV, bU);
        slotb += 8192; if (slotb == 24576) slotb = 0;
    }
#undef STEP
#undef STAGE
#undef BLOAD

    // ---- epilogue: C/D layout col = lane&15, row = 4*(lane>>4)+reg
    const int colbase = bn + wn * 64 + fr;
    const int rowbase = bm + wm * 128 + c16 * 4;
    #pragma unroll
    for (int n = 0; n < 4; ++n) {
        const int gc = colbase + n * 16;
        const bool seg0 = gc < Nsplit;
        OUT_T* op = seg0 ? out0 : out1;
        const int col = seg0 ? gc : gc - Nsplit;
        float bcol = 0.0f;
        if (BIAS_AXIS == 0) {
            const float* bp = seg0 ? bias0 : bias1;
            if (bp) bcol = bp[col];
        }
        #pragma unroll
        for (int m = 0; m < 8; ++m) {
            #pragma unroll
            for (int jj = 0; jj < 4; ++jj) {
                const int row = rowbase + m * 16 + jj;
                float v = acc[m][n][jj] * alpha;
                if (BIAS_AXIS == 0) v += bcol;
                else if (bias0)     v += bias0[row];
                store_out(&op[(long long)row * ldc + col], v);
            }
        }
    }
}

// ---------------------------------------------------------------------------
// fp32 -> bf16 elementwise convert (n multiple of 4)
// ---------------------------------------------------------------------------
__global__ __launch_bounds__(256) void f32_to_bf16(
    const float* __restrict__ in, bf16* __restrict__ out, long long n)
{
    long long i = ((long long)blockIdx.x * 256 + threadIdx.x) * 4;
    const long long stride = (long long)gridDim.x * 256 * 4;
    for (; i < n; i += stride) {
        float4 v = *reinterpret_cast<const float4*>(in + i);
        unsigned ux = __float_as_uint(v.x), uy = __float_as_uint(v.y);
        unsigned uz = __float_as_uint(v.z), uw = __float_as_uint(v.w);
        ushort4 o;
        o.x = (unsigned short)((ux + 0x7fffu + ((ux >> 16) & 1u)) >> 16);
        o.y = (unsigned short)((uy + 0x7fffu + ((uy >> 16) & 1u)) >> 16);
        o.z = (unsigned short)((uz + 0x7fffu + ((uz >> 16) & 1u)) >> 16);
        o.w = (unsigned short)((uw + 0x7fffu + ((uw >> 16) & 1u)) >> 16);
        *reinterpret_cast<ushort4*>(out + i) = o;
    }
}

// ---------------------------------------------------------------------------
// Transpose fp32 in [R][C] -> bf16 out [C][R]
// ---------------------------------------------------------------------------
__global__ void transpose_f32_bf16(const float* __restrict__ in,
                                   bf16* __restrict__ out, int R, int C)
{
    __shared__ float tile[32][33];
    const int c0 = blockIdx.x * 32, r0 = blockIdx.y * 32;
    const int tx = threadIdx.x, ty = threadIdx.y;
    #pragma unroll
    for (int i = ty; i < 32; i += 8)
        tile[i][tx] = in[(long long)(r0 + i) * C + (c0 + tx)];
    __syncthreads();
    #pragma unroll
    for (int i = ty; i < 32; i += 8)
        out[(long long)(c0 + i) * R + (r0 + tx)] = __float2bfloat16(tile[tx][i]);
}

// ---------------------------------------------------------------------------
// Row softmax, in-place on bf16 buffer, one 256-thread block per 2048-col row.
// ---------------------------------------------------------------------------
__global__ __launch_bounds__(256) void softmax_rows(bf16* __restrict__ Sbuf, int cols)
{
    __shared__ float red[8];
    bf16* p = Sbuf + (long long)blockIdx.x * cols;
    const int t = threadIdx.x;

    u16x8 v = *reinterpret_cast<const u16x8*>(p + t * 8);
    float f[8];
    #pragma unroll
    for (int i = 0; i < 8; ++i)
        f[i] = __uint_as_float((unsigned)v[i] << 16);

    float m = -3.0e38f;
    #pragma unroll
    for (int i = 0; i < 8; ++i) m = fmaxf(m, f[i]);
    #pragma unroll
    for (int o = 32; o; o >>= 1) m = fmaxf(m, __shfl_xor(m, o));
    if ((t & 63) == 0) red[t >> 6] = m;
    __syncthreads();
    m = fmaxf(fmaxf(red[0], red[1]), fmaxf(red[2], red[3]));

    float s = 0.0f;
    #pragma unroll
    for (int i = 0; i < 8; ++i) { f[i] = __expf(f[i] - m); s += f[i]; }
    #pragma unroll
    for (int o = 32; o; o >>= 1) s += __shfl_xor(s, o);
    __syncthreads();
    if ((t & 63) == 0) red[4 + (t >> 6)] = s;
    __syncthreads();
    s = (red[4] + red[5]) + (red[6] + red[7]);
    const float inv = 1.0f / s;

    u16x8 o16;
    #pragma unroll
    for (int i = 0; i < 8; ++i) {
        unsigned u = __float_as_uint(f[i] * inv);
        o16[i] = (unsigned short)((u + 0x7fffu + ((u >> 16) & 1u)) >> 16);  // RNE
    }
    *reinterpret_cast<u16x8*>(p + t * 8) = o16;
}

// ---------------------------------------------------------------------------
extern "C" void kernel_launch(void* const* d_in, const int* in_sizes, int n_in,
                              void* d_out, int out_size, void* d_ws, size_t ws_size,
                              hipStream_t stream)
{
    const int B = 8, S = 2048, D = 1024, H = 1024;
    const float* x  = (const float*)d_in[0];
    const float* Wq = (const float*)d_in[1];
    const float* bq = (const float*)d_in[2];
    const float* Wk = (const float*)d_in[3];
    const float* bk = (const float*)d_in[4];
    const float* Wv = (const float*)d_in[5];
    const float* bv = (const float*)d_in[6];
    float* out = (float*)d_out;

    const size_t nQKV = (size_t)B * S * H;
    const size_t nW   = (size_t)D * H;
    const long long sSH = (long long)S * H;
    const long long sSS = (long long)S * S;

    dim3 tb(32, 8), g256(256);
    const float inv_scale = 1.0f / 32.0f;    // 1/sqrt(H)

    // ws: xb | Q | K | Vt | WtQK(2nW) | Wtv(nW) | Sc
    bf16* xb   = (bf16*)d_ws;
    bf16* Q    = xb  + nQKV;
    bf16* Kb   = Q   + nQKV;
    bf16* Vt   = Kb  + nQKV;                 // [H][B*S], ld = B*S
    bf16* WtQK = Vt  + nQKV;
    bf16* Wtv  = WtQK + 2 * nW;
    bf16* Sc   = Wtv + nW;

    const size_t tierA = (4 * nQKV + 3 * nW + (size_t)B * S * S) * 2;
    const size_t tierB = (4 * nQKV + 3 * nW + (size_t)S * S) * 2;
    const bool bigA = ws_size >= tierA;
    if (ws_size < tierB) return;

    // 1. convert x; transpose weights
    f32_to_bf16<<<dim3(2048), g256, 0, stream>>>(x, xb, (long long)nQKV);
    transpose_f32_bf16<<<dim3(H / 32, D / 32), tb, 0, stream>>>(Wq, WtQK, D, H);
    transpose_f32_bf16<<<dim3(H / 32, D / 32), tb, 0, stream>>>(Wk, WtQK + nW, D, H);
    transpose_f32_bf16<<<dim3(H / 32, D / 32), tb, 0, stream>>>(Wv, Wtv, D, H);

    // 2. fused Q|K projection: [B*S,1024] x [2048,1024]^T -> Q, K (col-split)
    gemm_bm<bf16, 0><<<dim3(B * S / 256, 2 * H / 128, 1), g256, 0, stream>>>(
        xb, WtQK, bq, bk, Q, Kb, H, D, D, D, H, 0, 0, 0, 1.0f);

    // 3. V^T = Wv^T x^T : A=Wtv [H][D], Bt=xb [B*S][D] -> Vt [H][B*S], bias-by-row
    gemm_bm<bf16, 1><<<dim3(H / 256, B * S / 128, 1), g256, 0, stream>>>(
        Wtv, xb, bv, nullptr, Vt, nullptr, 1 << 30, D, D, D, B * S, 0, 0, 0, 1.0f);

    if (bigA) {
        // 4. scores = Q K^T / 32, batched
        gemm_bm<bf16, 0><<<dim3(S / 256, S / 128, B), g256, 0, stream>>>(
            Q, Kb, nullptr, nullptr, Sc, nullptr, 1 << 30, H, H, H, S,
            sSH, sSH, sSS, inv_scale);
        // 5. softmax rows in place
        softmax_rows<<<dim3(B * S), g256, 0, stream>>>(Sc, S);
        // 6. out = P V
        gemm_bm<float, 0><<<dim3(S / 256, H / 128, B), g256, 0, stream>>>(
            Sc, Vt, nullptr, nullptr, out, nullptr, 1 << 30, S, S, B * S, H,
            sSS, (long long)S, sSH, 1.0f);
    } else {
        for (int b = 0; b < B; ++b) {
            gemm_bm<bf16, 0><<<dim3(S / 256, S / 128, 1), g256, 0, stream>>>(
                Q + (size_t)b * sSH, Kb + (size_t)b * sSH, nullptr, nullptr,
                Sc, nullptr, 1 << 30, H, H, H, S, 0, 0, 0, inv_scale);
            softmax_rows<<<dim3(S), g256, 0, stream>>>(Sc, S);
            gemm_bm<float, 0><<<dim3(S / 256, H / 128, 1), g256, 0, stream>>>(
                Sc, Vt + (size_t)b * S, nullptr, nullptr,
                out + (size_t)b * sSH, nullptr, 1 << 30, S, S, B * S, H,
                0, 0, 0, 1.0f);
        }
    }
}

// Round 12
// 328.463 us; speedup vs baseline: 1.3421x; 1.3421x over previous
//
#include <hip/hip_runtime.h>
#include <hip/hip_bf16.h>
#include <stdint.h>

using bf16 = __hip_bfloat16;
typedef __bf16 bf16x8 __attribute__((ext_vector_type(8)));
typedef unsigned int u32x4 __attribute__((ext_vector_type(4)));   // 16B, align16
typedef float f32x4 __attribute__((ext_vector_type(4)));

#define GLOAD_LDS16(gp, lp)                                                    \
  __builtin_amdgcn_global_load_lds(                                           \
      (const __attribute__((address_space(1))) void*)(gp),                     \
      (__attribute__((address_space(3))) void*)(lp), 16, 0, 0)

#define WAITCNT_VM(N) asm volatile("s_waitcnt vmcnt(" #N ")" ::: "memory")
#define SB0() __builtin_amdgcn_sched_barrier(0)

__device__ inline void store_out(bf16* p, float v)  { *p = __float2bfloat16(v); }
__device__ inline void store_out(float* p, float v) { *p = v; }

// 16B LDS read via u32x4 (guaranteed ds_read_b128 path; __bf16-element vector
// derefs may legalize to narrower LDS ops -- round 12's single variable).
__device__ __forceinline__ bf16x8 ldsread16(const bf16* p) {
    u32x4 r = *reinterpret_cast<const u32x4*>(p);
    return __builtin_bit_cast(bf16x8, r);
}

// ---------------------------------------------------------------------------
// NT GEMM, 256x128 tile, BK=32, ring-3 LDS (72 KB -> 2 blocks/CU), counted
// vmcnt (T4), conflict-free swizzled LDS (T2), T1 chunked-XCD swizzle.
// == round-9 winner (83.7us big GEMMs, 818 TF) with ONE change: all LDS
// fragment reads typed u32x4 (b128-guaranteed) instead of __bf16-vector.
// 256 thr = 4 waves (2M x 2N), per-wave 128x64 out (8x4 frags 16x16x32).
// C[m][n] = alpha * sum_k A[m][k]*Bt[n][k] (+bias). Col-split epilogue.
// BIAS_AXIS: 0 per-col, 1 per-row. M mult 256, N mult 128, K mult 32 (>=64).
//
// LDS: 3 ring slots x 12288 elems (A 256x32 at +0, B 128x32 at +8192).
// Chunk (16B): row r (64B = 4 chunks), chunk col c stored at c ^ ((r>>1)&3);
// read elem(r,c16) = r*32 + ((c16 ^ ((r>>1)&3))*8  [measured 0 conflicts].
// Stage: thread t writes chunks {t+256k} linearly, src col pre-swizzled.
//
// Sync per step j: [12 ds_read_b128 (slot j%3); stage tile j+2 (6 gloads);
// 32 MFMA; vmcnt(6); s_barrier]. RAW: outstanding at step end = st(j+1) 6 +
// st(j+2) 6; vmcnt(6) drains st(j+1) -> resident after barrier. WAR: st(j+2)
// targets slot (j-1)%3 whose reads were consumed by step j-1 MFMAs (compiler
// lgkm waits) before its closing barrier. Tail: vmcnt(0)/none.
// ---------------------------------------------------------------------------
template <typename OUT_T, int BIAS_AXIS, bool NFAST>
__global__ __launch_bounds__(256, 2) void gemm_bm(
    const bf16* __restrict__ A, const bf16* __restrict__ Bt,
    const float* __restrict__ bias0, const float* __restrict__ bias1,
    OUT_T* __restrict__ out0, OUT_T* __restrict__ out1, int Nsplit,
    int K, int lda, int ldb, int ldc,
    long long sA, long long sB, long long sC, float alpha)
{
    __shared__ __align__(16) bf16 lds[36864];   // 72 KB: 3 x (8192 A + 4096 B)

    // ---- T1: chunked XCD swizzle + logical tile decode
    const int Mt = gridDim.x, Nt = gridDim.y;
    const int nwg = Mt * Nt * gridDim.z;
    const int hw  = blockIdx.x + Mt * (blockIdx.y + Nt * blockIdx.z);
    const int lg  = (nwg & 7) ? hw : ((hw & 7) * (nwg >> 3) + (hw >> 3));
    const int per = Mt * Nt;
    const int zt  = lg / per;
    const int rem = lg - zt * per;
    int mt, nt;
    if (NFAST) { mt = rem / Nt; nt = rem - mt * Nt; }
    else       { mt = rem % Mt; nt = rem / Mt; }

    A  += (long long)zt * sA;
    Bt += (long long)zt * sB;
    out0 += (long long)zt * sC;
    if (out1) out1 += (long long)zt * sC;

    const int bm = mt * 256;
    const int bn = nt * 128;
    const int t = threadIdx.x, lane = t & 63, w = t >> 6;
    const int wm = w >> 1, wn = w & 1;            // wave grid 2M x 2N
    const int fr = lane & 15, c16 = lane >> 4;

    // ---- staging src pointers: A chunks {t+256k, k<4}, B chunks {t+256k, k<2}
    const bf16* gA[4];
    const bf16* gB[2];
    #pragma unroll
    for (int k = 0; k < 4; ++k) {
        const int idx = t + 256 * k, r = idx >> 2, c = idx & 3;
        gA[k] = A + (long long)(bm + r) * lda + ((c ^ ((r >> 1) & 3)) << 3);
    }
    #pragma unroll
    for (int k = 0; k < 2; ++k) {
        const int idx = t + 256 * k, r = idx >> 2, c = idx & 3;
        gB[k] = Bt + (long long)(bn + r) * ldb + ((c ^ ((r >> 1) & 3)) << 3);
    }
    const int dstA = t * 8;            // + k*2048, elem offset in slot
    const int dstB = 8192 + t * 8;     // + k*2048

#define STAGE(JT, SLOTB) do {                                                  \
    GLOAD_LDS16(gA[0] + (JT) * 32, &lds[(SLOTB) + dstA]);                      \
    GLOAD_LDS16(gA[1] + (JT) * 32, &lds[(SLOTB) + dstA + 2048]);               \
    GLOAD_LDS16(gA[2] + (JT) * 32, &lds[(SLOTB) + dstA + 4096]);               \
    GLOAD_LDS16(gA[3] + (JT) * 32, &lds[(SLOTB) + dstA + 6144]);               \
    GLOAD_LDS16(gB[0] + (JT) * 32, &lds[(SLOTB) + dstB]);                      \
    GLOAD_LDS16(gB[1] + (JT) * 32, &lds[(SLOTB) + dstB + 2048]);               \
} while (0)

    // ---- fragment read offsets (elements), swizzled
    const int swz8 = (c16 ^ ((fr >> 1) & 3)) << 3;
    const int offA = (wm * 128 + fr) * 32 + swz8;          // + mf*512
    const int offB = 8192 + (wn * 64 + fr) * 32 + swz8;    // + nf*512

    const int nk = K >> 5;

    // prologue: stage tiles 0,1; drain tile 0 (keep 6 in flight)
    STAGE(0, 0); STAGE(1, 12288);
    WAITCNT_VM(6);
    __builtin_amdgcn_s_barrier();

    f32x4 acc[8][4] = {};

    int slotb = 0;
    for (int j = 0; j < nk; ++j) {
        SB0();   // region open

        bf16x8 af[8], bfv[4];
        #pragma unroll
        for (int m = 0; m < 8; ++m)
            af[m] = ldsread16(&lds[slotb + offA + m * 512]);
        #pragma unroll
        for (int n = 0; n < 4; ++n)
            bfv[n] = ldsread16(&lds[slotb + offB + n * 512]);

        if (j + 2 < nk) {
            int s2 = slotb + 24576; if (s2 >= 36864) s2 -= 36864;
            STAGE(j + 2, s2);
        }

        #pragma unroll
        for (int m = 0; m < 8; ++m)
            #pragma unroll
            for (int n = 0; n < 4; ++n)
                acc[m][n] = __builtin_amdgcn_mfma_f32_16x16x32_bf16(
                    af[m], bfv[n], acc[m][n], 0, 0, 0);

        SB0();   // region close
        if (j + 2 < nk)      { WAITCNT_VM(6); }
        else if (j + 1 < nk) { WAITCNT_VM(0); }
        __builtin_amdgcn_s_barrier();

        slotb += 12288; if (slotb == 36864) slotb = 0;
    }

    // ---- epilogue: C/D layout col = lane&15, row = 4*(lane>>4)+reg
    const int colbase = bn + wn * 64 + fr;
    const int rowbase = bm + wm * 128 + c16 * 4;
    #pragma unroll
    for (int n = 0; n < 4; ++n) {
        const int gc = colbase + n * 16;
        const bool seg0 = gc < Nsplit;
        OUT_T* op = seg0 ? out0 : out1;
        const int col = seg0 ? gc : gc - Nsplit;
        float bcol = 0.0f;
        if (BIAS_AXIS == 0) {
            const float* bp = seg0 ? bias0 : bias1;
            if (bp) bcol = bp[col];
        }
        #pragma unroll
        for (int m = 0; m < 8; ++m) {
            #pragma unroll
            for (int jj = 0; jj < 4; ++jj) {
                const int row = rowbase + m * 16 + jj;
                float v = acc[m][n][jj] * alpha;
                if (BIAS_AXIS == 0) v += bcol;
                else if (bias0)     v += bias0[row];
                store_out(&op[(long long)row * ldc + col], v);
            }
        }
    }
#undef STAGE
}

// ---------------------------------------------------------------------------
// fp32 -> bf16 elementwise convert (n multiple of 4)
// ---------------------------------------------------------------------------
__global__ __launch_bounds__(256) void f32_to_bf16(
    const float* __restrict__ in, bf16* __restrict__ out, long long n)
{
    long long i = ((long long)blockIdx.x * 256 + threadIdx.x) * 4;
    const long long stride = (long long)gridDim.x * 256 * 4;
    for (; i < n; i += stride) {
        float4 v = *reinterpret_cast<const float4*>(in + i);
        unsigned ux = __float_as_uint(v.x), uy = __float_as_uint(v.y);
        unsigned uz = __float_as_uint(v.z), uw = __float_as_uint(v.w);
        ushort4 o;
        o.x = (unsigned short)((ux + 0x7fffu + ((ux >> 16) & 1u)) >> 16);
        o.y = (unsigned short)((uy + 0x7fffu + ((uy >> 16) & 1u)) >> 16);
        o.z = (unsigned short)((uz + 0x7fffu + ((uz >> 16) & 1u)) >> 16);
        o.w = (unsigned short)((uw + 0x7fffu + ((uw >> 16) & 1u)) >> 16);
        *reinterpret_cast<ushort4*>(out + i) = o;
    }
}

// ---------------------------------------------------------------------------
// Transpose fp32 in [R][C] -> bf16 out [C][R]
// ---------------------------------------------------------------------------
__global__ void transpose_f32_bf16(const float* __restrict__ in,
                                   bf16* __restrict__ out, int R, int C)
{
    __shared__ float tile[32][33];
    const int c0 = blockIdx.x * 32, r0 = blockIdx.y * 32;
    const int tx = threadIdx.x, ty = threadIdx.y;
    #pragma unroll
    for (int i = ty; i < 32; i += 8)
        tile[i][tx] = in[(long long)(r0 + i) * C + (c0 + tx)];
    __syncthreads();
    #pragma unroll
    for (int i = ty; i < 32; i += 8)
        out[(long long)(c0 + i) * R + (r0 + tx)] = __float2bfloat16(tile[tx][i]);
}

// ---------------------------------------------------------------------------
// Row softmax, in-place on bf16 buffer, one 256-thread block per 2048-col row.
// Row load/store via u32x4 (b128/b128 path).
// ---------------------------------------------------------------------------
__global__ __launch_bounds__(256) void softmax_rows(bf16* __restrict__ Sbuf, int cols)
{
    __shared__ float red[8];
    bf16* p = Sbuf + (long long)blockIdx.x * cols;
    const int t = threadIdx.x;

    u32x4 v = *reinterpret_cast<const u32x4*>(p + t * 8);
    float f[8];
    #pragma unroll
    for (int i = 0; i < 4; ++i) {
        f[2 * i]     = __uint_as_float(v[i] << 16);
        f[2 * i + 1] = __uint_as_float(v[i] & 0xffff0000u);
    }

    float m = -3.0e38f;
    #pragma unroll
    for (int i = 0; i < 8; ++i) m = fmaxf(m, f[i]);
    #pragma unroll
    for (int o = 32; o; o >>= 1) m = fmaxf(m, __shfl_xor(m, o));
    if ((t & 63) == 0) red[t >> 6] = m;
    __syncthreads();
    m = fmaxf(fmaxf(red[0], red[1]), fmaxf(red[2], red[3]));

    float s = 0.0f;
    #pragma unroll
    for (int i = 0; i < 8; ++i) { f[i] = __expf(f[i] - m); s += f[i]; }
    #pragma unroll
    for (int o = 32; o; o >>= 1) s += __shfl_xor(s, o);
    __syncthreads();
    if ((t & 63) == 0) red[4 + (t >> 6)] = s;
    __syncthreads();
    s = (red[4] + red[5]) + (red[6] + red[7]);
    const float inv = 1.0f / s;

    u32x4 o16;
    #pragma unroll
    for (int i = 0; i < 4; ++i) {
        unsigned ua = __float_as_uint(f[2 * i] * inv);
        unsigned ub = __float_as_uint(f[2 * i + 1] * inv);
        ua = (ua + 0x7fffu + ((ua >> 16) & 1u)) >> 16;          // RNE
        ub = (ub + 0x7fffu + ((ub >> 16) & 1u)) & 0xffff0000u;  // RNE, hi half
        o16[i] = ua | ub;
    }
    *reinterpret_cast<u32x4*>(p + t * 8) = o16;
}

// ---------------------------------------------------------------------------
extern "C" void kernel_launch(void* const* d_in, const int* in_sizes, int n_in,
                              void* d_out, int out_size, void* d_ws, size_t ws_size,
                              hipStream_t stream)
{
    const int B = 8, S = 2048, D = 1024, H = 1024;
    const float* x  = (const float*)d_in[0];
    const float* Wq = (const float*)d_in[1];
    const float* bq = (const float*)d_in[2];
    const float* Wk = (const float*)d_in[3];
    const float* bk = (const float*)d_in[4];
    const float* Wv = (const float*)d_in[5];
    const float* bv = (const float*)d_in[6];
    float* out = (float*)d_out;

    const size_t nQKV = (size_t)B * S * H;
    const size_t nW   = (size_t)D * H;
    const long long sSH = (long long)S * H;
    const long long sSS = (long long)S * S;

    dim3 tb(32, 8), g256(256);
    const float inv_scale = 1.0f / 32.0f;    // 1/sqrt(H)

    // ws: xb | Q | K | Vt | WtQK(2nW) | Wtv(nW) | Sc
    bf16* xb   = (bf16*)d_ws;
    bf16* Q    = xb  + nQKV;
    bf16* Kb   = Q   + nQKV;
    bf16* Vt   = Kb  + nQKV;                 // [H][B*S], ld = B*S
    bf16* WtQK = Vt  + nQKV;
    bf16* Wtv  = WtQK + 2 * nW;
    bf16* Sc   = Wtv + nW;

    const size_t tierA = (4 * nQKV + 3 * nW + (size_t)B * S * S) * 2;
    const size_t tierB = (4 * nQKV + 3 * nW + (size_t)S * S) * 2;
    const bool bigA = ws_size >= tierA;
    if (ws_size < tierB) return;

    // 1. convert x; transpose weights
    f32_to_bf16<<<dim3(2048), g256, 0, stream>>>(x, xb, (long long)nQKV);
    transpose_f32_bf16<<<dim3(H / 32, D / 32), tb, 0, stream>>>(Wq, WtQK, D, H);
    transpose_f32_bf16<<<dim3(H / 32, D / 32), tb, 0, stream>>>(Wk, WtQK + nW, D, H);
    transpose_f32_bf16<<<dim3(H / 32, D / 32), tb, 0, stream>>>(Wv, Wtv, D, H);

    // 2. fused Q|K projection: [B*S,1024] x [2048,1024]^T -> Q, K (col-split)
    gemm_bm<bf16, 0, true><<<dim3(B * S / 256, 2 * H / 128, 1), g256, 0, stream>>>(
        xb, WtQK, bq, bk, Q, Kb, H, D, D, D, H, 0, 0, 0, 1.0f);

    // 3. V^T = Wv^T x^T : A=Wtv [H][D], Bt=xb [B*S][D] -> Vt [H][B*S], bias-by-row
    gemm_bm<bf16, 1, false><<<dim3(H / 256, B * S / 128, 1), g256, 0, stream>>>(
        Wtv, xb, bv, nullptr, Vt, nullptr, 1 << 30, D, D, D, B * S, 0, 0, 0, 1.0f);

    if (bigA) {
        // 4. scores = Q K^T / 32, batched
        gemm_bm<bf16, 0, true><<<dim3(S / 256, S / 128, B), g256, 0, stream>>>(
            Q, Kb, nullptr, nullptr, Sc, nullptr, 1 << 30, H, H, H, S,
            sSH, sSH, sSS, inv_scale);
        // 5. softmax rows in place
        softmax_rows<<<dim3(B * S), g256, 0, stream>>>(Sc, S);
        // 6. out = P V
        gemm_bm<float, 0, true><<<dim3(S / 256, H / 128, B), g256, 0, stream>>>(
            Sc, Vt, nullptr, nullptr, out, nullptr, 1 << 30, S, S, B * S, H,
            sSS, (long long)S, sSH, 1.0f);
    } else {
        for (int b = 0; b < B; ++b) {
            gemm_bm<bf16, 0, true><<<dim3(S / 256, S / 128, 1), g256, 0, stream>>>(
                Q + (size_t)b * sSH, Kb + (size_t)b * sSH, nullptr, nullptr,
                Sc, nullptr, 1 << 30, H, H, H, S, 0, 0, 0, inv_scale);
            softmax_rows<<<dim3(S), g256, 0, stream>>>(Sc, S);
            gemm_bm<float, 0, true><<<dim3(S / 256, H / 128, 1), g256, 0, stream>>>(
                Sc, Vt + (size_t)b * S, nullptr, nullptr,
                out + (size_t)b * sSH, nullptr, 1 << 30, S, S, B * S, H,
                0, 0, 0, 1.0f);
        }
    }
}